// Round 6
// baseline (479.470 us; speedup 1.0000x reference)
//
#include <hip/hip_runtime.h>
#include <cstdint>
#include <cstddef>

#define B_   4096
#define T_   128
#define IN_  768
#define H_   256
#define BM_  128          // batch rows per workgroup (one 128-row x tile)
#define KC1  (IN_ / 32)   // 24 k-chunks, layer 1
#define KC2  (H_ / 32)    // 8  k-chunks, layer 2 (16 half-chunks)

typedef __bf16 bf16_t;
typedef bf16_t bf16x8 __attribute__((ext_vector_type(8)));
typedef bf16_t bf16x4 __attribute__((ext_vector_type(4)));
typedef float  floatx16 __attribute__((ext_vector_type(16)));

#define MFMA32(a, b, c) __builtin_amdgcn_mfma_f32_32x32x16_bf16((a), (b), (c), 0, 0, 0)

// Counted-vmcnt barriers (T3/T4): never drain vmcnt to 0 in steady-state loops.
// EVERY barrier carries lgkmcnt(0): a bare s_barrier does NOT guarantee this
// wave's ds_reads have sampled LDS before other waves' post-barrier
// global_load_lds writes land (out-of-band LDS write path, ~150-200cy) — that
// WAR race was round-3's correctness failure. lgkmcnt(0) pins + drains the
// reads pre-barrier, closing it.
#define WAITBAR(N) asm volatile("s_waitcnt vmcnt(" #N ") lgkmcnt(0)\n\ts_barrier" ::: "memory")
#define WAIT_LGK_BAR() asm volatile("s_waitcnt lgkmcnt(0)\n\ts_barrier" ::: "memory")

__device__ __forceinline__ void gl_lds16(const bf16_t* g, bf16_t* l) {
    __builtin_amdgcn_global_load_lds(
        (const __attribute__((address_space(1))) void*)g,
        (__attribute__((address_space(3))) void*)l, 16, 0, 0);
}

// ---------- prep bodies (merged into one dispatch) ----------
// W [t][K][H] fp32 -> A-frag tiles [t][kc][kq=4][h=256][8k] bf16
__device__ __forceinline__ void tile_w_body(const float* __restrict__ src,
                                            bf16_t* __restrict__ dst,
                                            int K, int KC, int blk) {
    const int t  = blk / KC;
    const int kc = blk - t * KC;
    const int kq = threadIdx.x >> 6;           // 0..3
    const int h4 = (threadIdx.x & 63) * 4;     // 0..252
    const float* s = src + ((size_t)t * K + kc * 32 + kq * 8) * H_ + h4;
    float r[8][4];
#pragma unroll
    for (int e = 0; e < 8; ++e) {
        float4 v = *(const float4*)(s + (size_t)e * H_);
        r[e][0] = v.x; r[e][1] = v.y; r[e][2] = v.z; r[e][3] = v.w;
    }
    bf16_t* d = dst + (((size_t)(t * KC + kc) * 4 + kq) * H_ + h4) * 8;
#pragma unroll
    for (int c = 0; c < 4; ++c) {
        bf16x8 v;
#pragma unroll
        for (int e = 0; e < 8; ++e) v[e] = (bf16_t)r[e][c];
        *(bf16x8*)(d + c * 8) = v;
    }
}

// x [B][IN] fp32 -> B-frag tiles [mblk=32][kc][kq=4][m=128][8k] bf16
__device__ __forceinline__ void tile_x_body(const float* __restrict__ src,
                                            bf16_t* __restrict__ dst, long long o) {
    int m = (int)(o & 127);
    long long q = o >> 7;
    int kq = (int)(q & 3);
    int q2 = (int)(q >> 2);
    int kc   = q2 % KC1;
    int mblk = q2 / KC1;
    const float* s = src + ((long long)mblk * 128 + m) * IN_ + kc * 32 + kq * 8;
    float4 a = *(const float4*)s;
    float4 b = *(const float4*)(s + 4);
    bf16x8 v;
    v[0] = (bf16_t)a.x; v[1] = (bf16_t)a.y; v[2] = (bf16_t)a.z; v[3] = (bf16_t)a.w;
    v[4] = (bf16_t)b.x; v[5] = (bf16_t)b.y; v[6] = (bf16_t)b.z; v[7] = (bf16_t)b.w;
    *(bf16x8*)(dst + o * 8) = v;
}

// One dispatch for all three conversions: block ranges select the body.
// tile_x: 1536 blocks; W1: 128*24=3072; W2: 128*8=1024. Total 5632.
__global__ __launch_bounds__(256)
void prep_all(const float* __restrict__ x,  bf16_t* __restrict__ xt,
              const float* __restrict__ W1, bf16_t* __restrict__ w1t,
              const float* __restrict__ W2, bf16_t* __restrict__ w2t) {
    const int b = blockIdx.x;
    if (b < 1536) {
        long long o = (long long)b * 256 + threadIdx.x;   // < 393216 exactly
        tile_x_body(x, xt, o);
    } else if (b < 1536 + 3072) {
        tile_w_body(W1, w1t, IN_, KC1, b - 1536);
    } else {
        tile_w_body(W2, w2t, H_, KC2, b - 4608);
    }
}

// ---------- fused per-task MLP: 256 threads, 128 batch rows, 2 WG/CU.
// Two independent WGs co-reside per CU (LDS 64K hbuf + 16K wt2 = 80 KB): same
// per-CU MFMA/LDS totals as the 512-thread version, but the two WGs' barriers
// are independent -> one WG's compute hides the other's barrier convergence
// and load waits. Layer-1: ring-2 24KB chunk slots inside hbuf, WAITBAR(6)
// counted-vmcnt RAW, lgkmcnt(0)-guarded barrier before every restage (WAR).
// Layer-2: ring-2 of 8KB W2 half-chunks in wt2, WAITBAR(2); W2 halves 0/1
// issued in the layer-1 tail. hbuf layout [blk=h/8][m=128][8h] bf16: epilogue
// b64 stores, layer2 B-frag b128 reads, layer3 reads all lane-contiguous. ----
__global__ __launch_bounds__(256, 2)
void mtmlp_fused4(const bf16_t* __restrict__ xt, const bf16_t* __restrict__ w1t,
                  const float* __restrict__ b1, const bf16_t* __restrict__ w2t,
                  const float* __restrict__ b2, const float* __restrict__ W3,
                  const float* __restrict__ b3, float* __restrict__ out) {
    // XCD-locality swizzle: XCD k owns tasks [16k,16k+16) (32 mblks each);
    // W1[t]/W2[t] stay L2-resident per XCD.
    const int L    = blockIdx.x;          // 0..4095
    const int xcd  = L & 7;
    const int slot = L >> 3;              // 0..511
    const int t    = xcd * 16 + (slot >> 5);
    const int mblk = slot & 31;
    const int m0   = mblk * BM_;

    const int tid  = threadIdx.x;
    const int lane = tid & 63;
    const int wid  = tid >> 6;            // 0..3
    const int wm   = wid >> 1;            // 0..1 : h half (128)
    const int wn   = wid & 1;             // 0..1 : m half (64)
    const int ln31 = lane & 31;
    const int hi   = lane >> 5;

    __shared__ __align__(16) bf16_t hbuf[BM_ * H_];      // 64 KB: L1 ring-2, then h1/h2
    __shared__ __align__(16) bf16_t wt2[2 * 2 * H_ * 8]; // 16 KB: L2 half-chunk ring-2
    float* w3s = (float*)wt2;

    floatx16 acc[4][2];
#pragma unroll
    for (int i = 0; i < 4; ++i)
#pragma unroll
        for (int j = 0; j < 2; ++j)
#pragma unroll
            for (int e = 0; e < 16; ++e) acc[i][j][e] = 0.0f;

    const bf16_t* w1base = w1t + (size_t)t * KC1 * 8192;
    const bf16_t* w2base = w2t + (size_t)t * KC2 * 8192;
    const bf16_t* xbase  = xt + (size_t)mblk * KC1 * 4096;

    auto stage1 = [&](bf16_t* buf, int kc) {               // 6 vmcnt ops: 16K W + 8K x
        const bf16_t* ws = w1base + (size_t)kc * 8192;
        gl_lds16(ws + tid * 8,        buf + tid * 8);
        gl_lds16(ws + 2048 + tid * 8, buf + 2048 + tid * 8);
        gl_lds16(ws + 4096 + tid * 8, buf + 4096 + tid * 8);
        gl_lds16(ws + 6144 + tid * 8, buf + 6144 + tid * 8);
        const bf16_t* xs = xbase + (size_t)kc * 4096;
        gl_lds16(xs + tid * 8,        buf + 8192 + tid * 8);
        gl_lds16(xs + 2048 + tid * 8, buf + 10240 + tid * 8);
    };
    auto stage2h = [&](bf16_t* dst, int n) {               // 2 vmcnt ops: 8K half-chunk
        const bf16_t* ws = w2base + (size_t)n * 4096;
        gl_lds16(ws + tid * 8,        dst + tid * 8);
        gl_lds16(ws + 2048 + tid * 8, dst + 2048 + tid * 8);
    };
    auto comp1 = [&](const bf16_t* buf) {
#pragma unroll
        for (int s = 0; s < 2; ++s) {
            const int kq = s * 2 + hi;
            bf16x8 A[4], Bf[2];
#pragma unroll
            for (int i = 0; i < 4; ++i)
                A[i] = *(const bf16x8*)(buf + (size_t)(kq * H_ + wm * 128 + i * 32 + ln31) * 8);
#pragma unroll
            for (int j = 0; j < 2; ++j) {
                const int mm = wn * 64 + j * 32 + ln31;
                Bf[j] = *(const bf16x8*)(buf + 8192 + (size_t)(kq * 128 + mm) * 8);
            }
#pragma unroll
            for (int i = 0; i < 4; ++i)
#pragma unroll
                for (int j = 0; j < 2; ++j) acc[i][j] = MFMA32(A[i], Bf[j], acc[i][j]);
        }
    };
    // layer-2 compute on one half-chunk n (kq pair): local kq = hi, blk = 2n+hi.
    auto comp2 = [&](const bf16_t* wbuf, int n) {
        bf16x8 A[4], Bf[2];
#pragma unroll
        for (int i = 0; i < 4; ++i)
            A[i] = *(const bf16x8*)(wbuf + (size_t)(hi * H_ + wm * 128 + i * 32 + ln31) * 8);
        const int blk = n * 2 + hi;
#pragma unroll
        for (int j = 0; j < 2; ++j) {
            const int mm = wn * 64 + j * 32 + ln31;
            Bf[j] = *(const bf16x8*)(hbuf + (size_t)(blk * BM_ + mm) * 8);
        }
#pragma unroll
        for (int i = 0; i < 4; ++i)
#pragma unroll
            for (int j = 0; j < 2; ++j) acc[i][j] = MFMA32(A[i], Bf[j], acc[i][j]);
    };

    // ---------------- layer 1: h1^T = W1^T · x^T (ring-2, 24KB slots) ----------------
    bf16_t* s0 = hbuf;
    bf16_t* s1 = hbuf + 12288;
    stage1(s0, 0);
    stage1(s1, 1);                                     // 12 loads in flight
    for (int p = 0; p < 11; ++p) {                     // kc = 2p, 2p+1  (0..21)
        WAITBAR(6); comp1(s0); WAIT_LGK_BAR(); stage1(s0, 2 * p + 2);
        WAITBAR(6); comp1(s1); WAIT_LGK_BAR(); stage1(s1, 2 * p + 3);
    }
    // Tail: kc=22,23; W2 halves 0,1 issued under kc=23 + epilogue-1.
    WAITBAR(6); comp1(s0); WAIT_LGK_BAR(); stage2h(wt2, 0); stage2h(wt2 + 4096, 1);
    WAITBAR(4); comp1(s1); WAIT_LGK_BAR();   // kc=23 done; W2 h0,h1 still in flight

    // epilogue 1: bias + relu -> hbuf [blk][m][8]
#pragma unroll
    for (int i = 0; i < 4; ++i) {
#pragma unroll
        for (int g = 0; g < 4; ++g) {
            const int h0 = wm * 128 + i * 32 + g * 8 + 4 * hi;
            float4 bias = *(const float4*)(b1 + t * H_ + h0);
            const int blk = h0 >> 3;
#pragma unroll
            for (int j = 0; j < 2; ++j) {
                const int mm = wn * 64 + j * 32 + ln31;
                bf16x4 o;
                o[0] = (bf16_t)fmaxf(acc[i][j][4 * g + 0] + bias.x, 0.0f);
                o[1] = (bf16_t)fmaxf(acc[i][j][4 * g + 1] + bias.y, 0.0f);
                o[2] = (bf16_t)fmaxf(acc[i][j][4 * g + 2] + bias.z, 0.0f);
                o[3] = (bf16_t)fmaxf(acc[i][j][4 * g + 3] + bias.w, 0.0f);
                *(bf16x4*)(hbuf + (size_t)(blk * BM_ + mm) * 8 + 4 * hi) = o;
            }
        }
    }

#pragma unroll
    for (int i = 0; i < 4; ++i)
#pragma unroll
        for (int j = 0; j < 2; ++j)
#pragma unroll
            for (int e = 0; e < 16; ++e) acc[i][j][e] = 0.0f;

    // ---------------- layer 2: h2^T = W2^T · h1^T (half-chunk ring-2) ----------------
    for (int np = 0; np < 8; ++np) {                   // halves n = 2np, 2np+1 (0..15)
        const int n0 = 2 * np, n1 = 2 * np + 1;
        WAITBAR(2);                                    // own h(n0) done, h(n0+1) in flight
        comp2(wt2, n0); WAIT_LGK_BAR();
        if (n0 < 14) stage2h(wt2, n0 + 2);
        if (n1 < 15) { WAITBAR(2); } else { WAITBAR(0); }
        comp2(wt2 + 4096, n1); WAIT_LGK_BAR();
        if (n1 < 14) stage2h(wt2 + 4096, n1 + 2);
    }

    // epilogue 2: bias + relu -> h2 (hbuf, same layout); stage W3 into w3s
    w3s[tid] = W3[t * H_ + tid];                       // 256 threads = H_ floats
#pragma unroll
    for (int i = 0; i < 4; ++i) {
#pragma unroll
        for (int g = 0; g < 4; ++g) {
            const int h0 = wm * 128 + i * 32 + g * 8 + 4 * hi;
            float4 bias = *(const float4*)(b2 + t * H_ + h0);
            const int blk = h0 >> 3;
#pragma unroll
            for (int j = 0; j < 2; ++j) {
                const int mm = wn * 64 + j * 32 + ln31;
                bf16x4 o;
                o[0] = (bf16_t)fmaxf(acc[i][j][4 * g + 0] + bias.x, 0.0f);
                o[1] = (bf16_t)fmaxf(acc[i][j][4 * g + 1] + bias.y, 0.0f);
                o[2] = (bf16_t)fmaxf(acc[i][j][4 * g + 2] + bias.z, 0.0f);
                o[3] = (bf16_t)fmaxf(acc[i][j][4 * g + 3] + bias.w, 0.0f);
                *(bf16x4*)(hbuf + (size_t)(blk * BM_ + mm) * 8 + 4 * hi) = o;
            }
        }
    }
    WAIT_LGK_BAR();   // own ds_writes drained, then barrier: h2 + w3s visible

    // ---------------- layer 3: out[m,t] = h2[m,:]·W3[t,:] + b3[t] ----------------
    {
        const int m = tid >> 1, seg = tid & 1;   // 2 threads/row, 128 h each
        float sum = 0.0f;
#pragma unroll
        for (int b = 0; b < 16; ++b) {
            const int blk = seg * 16 + b;
            const bf16x8 v = *(const bf16x8*)(hbuf + (size_t)(blk * BM_ + m) * 8);
            const float* w = w3s + blk * 8;
#pragma unroll
            for (int e = 0; e < 8; ++e) sum += (float)v[e] * w[e];
        }
        sum += __shfl_xor(sum, 1);
        if (seg == 0) out[(size_t)(m0 + m) * T_ + t] = sum + b3[t];
    }
}

extern "C" void kernel_launch(void* const* d_in, const int* in_sizes, int n_in,
                              void* d_out, int out_size, void* d_ws, size_t ws_size,
                              hipStream_t stream) {
    const float* x  = (const float*)d_in[0];
    const float* W1 = (const float*)d_in[1];
    const float* b1 = (const float*)d_in[2];
    const float* W2 = (const float*)d_in[3];
    const float* b2 = (const float*)d_in[4];
    const float* W3 = (const float*)d_in[5];
    const float* b3 = (const float*)d_in[6];
    float* out = (float*)d_out;

    const size_t nx  = (size_t)B_ * IN_;        // 3,145,728
    const size_t nw1 = (size_t)T_ * IN_ * H_;   // 25,165,824

    bf16_t* xt  = (bf16_t*)d_ws;
    bf16_t* w1t = xt + nx;
    bf16_t* w2t = w1t + nw1;

    prep_all<<<dim3(5632), 256, 0, stream>>>(x, xt, W1, w1t, W2, w2t);
    mtmlp_fused4<<<dim3(4096), 256, 0, stream>>>(xt, w1t, b1, w2t, b2, W3, b3, out);
}

// Round 11
// 456.810 us; speedup vs baseline: 1.0496x; 1.0496x over previous
//
#include <hip/hip_runtime.h>
#include <cstdint>
#include <cstddef>

#define B_   4096
#define T_   128
#define IN_  768
#define H_   256
#define BM_  256          // batch rows per workgroup (two 128-row x tiles)
#define KC1  (IN_ / 32)   // 24 k-chunks, layer 1
#define KC2  (H_ / 32)    // 8  k-chunks, layer 2

typedef __bf16 bf16_t;
typedef bf16_t bf16x8 __attribute__((ext_vector_type(8)));
typedef bf16_t bf16x4 __attribute__((ext_vector_type(4)));
typedef float  floatx16 __attribute__((ext_vector_type(16)));

#define MFMA32(a, b, c) __builtin_amdgcn_mfma_f32_32x32x16_bf16((a), (b), (c), 0, 0, 0)

// Counted-vmcnt barriers (T3/T4): never drain vmcnt to 0 in steady-state loops.
// EVERY barrier carries lgkmcnt(0): drains this wave's ds_reads pre-barrier so a
// post-barrier global_load_lds restage can't WAR-race them (round-3 lesson).
#define WAITBAR(N) asm volatile("s_waitcnt vmcnt(" #N ") lgkmcnt(0)\n\ts_barrier" ::: "memory")
#define WAIT_LGK_BAR() asm volatile("s_waitcnt lgkmcnt(0)\n\ts_barrier" ::: "memory")

__device__ __forceinline__ void gl_lds16(const bf16_t* g, bf16_t* l) {
    __builtin_amdgcn_global_load_lds(
        (const __attribute__((address_space(1))) void*)g,
        (__attribute__((address_space(3))) void*)l, 16, 0, 0);
}

// ---------- prep bodies (merged into one dispatch) ----------
// W [t][K][H] fp32 -> A-frag tiles [t][kc][kq=4][h=256][8k] bf16
__device__ __forceinline__ void tile_w_body(const float* __restrict__ src,
                                            bf16_t* __restrict__ dst,
                                            int K, int KC, int blk) {
    const int t  = blk / KC;
    const int kc = blk - t * KC;
    const int kq = threadIdx.x >> 6;           // 0..3
    const int h4 = (threadIdx.x & 63) * 4;     // 0..252
    const float* s = src + ((size_t)t * K + kc * 32 + kq * 8) * H_ + h4;
    float r[8][4];
#pragma unroll
    for (int e = 0; e < 8; ++e) {
        float4 v = *(const float4*)(s + (size_t)e * H_);
        r[e][0] = v.x; r[e][1] = v.y; r[e][2] = v.z; r[e][3] = v.w;
    }
    bf16_t* d = dst + (((size_t)(t * KC + kc) * 4 + kq) * H_ + h4) * 8;
#pragma unroll
    for (int c = 0; c < 4; ++c) {
        bf16x8 v;
#pragma unroll
        for (int e = 0; e < 8; ++e) v[e] = (bf16_t)r[e][c];
        *(bf16x8*)(d + c * 8) = v;
    }
}

// x [B][IN] fp32 -> B-frag tiles [mblk=32][kc][kq=4][m=128][8k] bf16
__device__ __forceinline__ void tile_x_body(const float* __restrict__ src,
                                            bf16_t* __restrict__ dst, long long o) {
    int m = (int)(o & 127);
    long long q = o >> 7;
    int kq = (int)(q & 3);
    int q2 = (int)(q >> 2);
    int kc   = q2 % KC1;
    int mblk = q2 / KC1;
    const float* s = src + ((long long)mblk * 128 + m) * IN_ + kc * 32 + kq * 8;
    float4 a = *(const float4*)s;
    float4 b = *(const float4*)(s + 4);
    bf16x8 v;
    v[0] = (bf16_t)a.x; v[1] = (bf16_t)a.y; v[2] = (bf16_t)a.z; v[3] = (bf16_t)a.w;
    v[4] = (bf16_t)b.x; v[5] = (bf16_t)b.y; v[6] = (bf16_t)b.z; v[7] = (bf16_t)b.w;
    *(bf16x8*)(dst + o * 8) = v;
}

__global__ __launch_bounds__(256)
void prep_all(const float* __restrict__ x,  bf16_t* __restrict__ xt,
              const float* __restrict__ W1, bf16_t* __restrict__ w1t,
              const float* __restrict__ W2, bf16_t* __restrict__ w2t) {
    const int b = blockIdx.x;
    if (b < 1536) {
        long long o = (long long)b * 256 + threadIdx.x;   // < 393216 exactly
        tile_x_body(x, xt, o);
    } else if (b < 1536 + 3072) {
        tile_w_body(W1, w1t, IN_, KC1, b - 1536);
    } else {
        tile_w_body(W2, w2t, H_, KC2, b - 4608);
    }
}

// ---------- fused MLP: 512 threads, 256 rows, 1 WG/CU (R2 structure) ----------
// x (B-operand) does not go through LDS: each wave loads its private
// B-fragments (4 x bf16x8 per chunk) straight from global into named
// registers, ring-2 (xA/xB), prefetched 2 chunks ahead. This cuts L1-loop LDS
// traffic from 96KB read + 32KB write per chunk to 64KB + 16KB (the dominant
// pipe per the R2 budget), and removes x from the barrier/WAR machinery.
// W1 stays in LDS (shared by 4 waves): ring-4 of 16KB W-only slots in hbuf,
// counted vmcnt (6-op iteration blocks = 2 W-gl_lds + 4 x-loads, barrier-
// pinned -> steady WAITBAR(6)). Layer 2/3 identical to R2, lgkm-hardened.
__global__ __launch_bounds__(512, 2)
void mtmlp_fused5(const bf16_t* __restrict__ xt, const bf16_t* __restrict__ w1t,
                  const float* __restrict__ b1, const bf16_t* __restrict__ w2t,
                  const float* __restrict__ b2, const float* __restrict__ W3,
                  const float* __restrict__ b3, float* __restrict__ out) {
    const int L    = blockIdx.x;          // 0..2047
    const int xcd  = L & 7;
    const int slot = L >> 3;              // 0..255
    const int t    = xcd * 16 + (slot >> 4);
    const int mblk = slot & 15;
    const int m0   = mblk * BM_;
    const int mb0  = mblk * 2;            // 128-row tile index

    const int tid  = threadIdx.x;
    const int lane = tid & 63;
    const int wid  = tid >> 6;            // 0..7
    const int wm   = wid >> 2;            // 0..1 : h half (128)
    const int wn   = wid & 3;             // 0..3 : m quarter (64)
    const int ln31 = lane & 31;
    const int hi   = lane >> 5;

    __shared__ __align__(16) bf16_t hbuf[BM_ * H_];       // 128 KB: W ring-4 (64K), then h1/h2
    __shared__ __align__(16) bf16_t wt2[2 * 4 * H_ * 8];  // 32 KB: L2 W2 ring-2; w3s alias
    float* w3s = (float*)wt2;

    floatx16 acc[4][2];
#pragma unroll
    for (int i = 0; i < 4; ++i)
#pragma unroll
        for (int j = 0; j < 2; ++j)
#pragma unroll
            for (int e = 0; e < 16; ++e) acc[i][j][e] = 0.0f;

    const bf16_t* w1base = w1t + (size_t)t * KC1 * 8192;
    const bf16_t* w2base = w2t + (size_t)t * KC2 * 8192;
    // per-wave x base: 128-row tile (mb0 + wn>>1), row base (wn&1)*64
    const bf16_t* xw = xt + (size_t)(mb0 + (wn >> 1)) * KC1 * 4096;
    // element offsets inside a 4096-elem x chunk: +S*2048 +J*256 added statically
    const int lbase = hi * 1024 + (wn & 1) * 512 + ln31 * 8;
    // element offsets inside an 8192-elem W slot: +S*4096 +I*256 added statically
    const int abase = hi * 2048 + wm * 1024 + ln31 * 8;

    bf16_t* const sl0 = hbuf;
    bf16_t* const sl1 = hbuf + 8192;
    bf16_t* const sl2 = hbuf + 16384;
    bf16_t* const sl3 = hbuf + 24576;

    auto stageW = [&](bf16_t* dst, int kc) {               // 2 vmcnt ops: 16KB W chunk
        const bf16_t* ws = w1base + (size_t)kc * 8192;
        gl_lds16(ws + tid * 8,        dst + tid * 8);
        gl_lds16(ws + 4096 + tid * 8, dst + 4096 + tid * 8);
    };
    auto stage2 = [&](bf16_t* dst, int kc) {               // 2 vmcnt ops: 16KB W2 chunk
        const bf16_t* ws = w2base + (size_t)kc * 8192;
        gl_lds16(ws + tid * 8,        dst + tid * 8);
        gl_lds16(ws + 4096 + tid * 8, dst + 4096 + tid * 8);
    };

// x B-fragments: 4 global 16B loads into named registers (static, rule #20).
#define LOADX(XV, kcc) do {                                          \
        const bf16_t* xp_ = xw + (size_t)(kcc) * 4096;               \
        XV##0 = *(const bf16x8*)(xp_ + lbase + 0 * 2048 + 0 * 256);  \
        XV##1 = *(const bf16x8*)(xp_ + lbase + 0 * 2048 + 1 * 256);  \
        XV##2 = *(const bf16x8*)(xp_ + lbase + 1 * 2048 + 0 * 256);  \
        XV##3 = *(const bf16x8*)(xp_ + lbase + 1 * 2048 + 1 * 256);  \
    } while (0)

// A from LDS slot, B from registers. 8 ds_read_b128 + 16 MFMA per chunk.
#define COMP1(bp_, XV) do {                                          \
        const bf16_t* b_ = (bp_);                                    \
        bf16x8 A0_, A1_, A2_, A3_;                                   \
        A0_ = *(const bf16x8*)(b_ + abase + 0 * 4096 + 0 * 256);     \
        A1_ = *(const bf16x8*)(b_ + abase + 0 * 4096 + 1 * 256);     \
        A2_ = *(const bf16x8*)(b_ + abase + 0 * 4096 + 2 * 256);     \
        A3_ = *(const bf16x8*)(b_ + abase + 0 * 4096 + 3 * 256);     \
        acc[0][0] = MFMA32(A0_, XV##0, acc[0][0]);                   \
        acc[0][1] = MFMA32(A0_, XV##1, acc[0][1]);                   \
        acc[1][0] = MFMA32(A1_, XV##0, acc[1][0]);                   \
        acc[1][1] = MFMA32(A1_, XV##1, acc[1][1]);                   \
        acc[2][0] = MFMA32(A2_, XV##0, acc[2][0]);                   \
        acc[2][1] = MFMA32(A2_, XV##1, acc[2][1]);                   \
        acc[3][0] = MFMA32(A3_, XV##0, acc[3][0]);                   \
        acc[3][1] = MFMA32(A3_, XV##1, acc[3][1]);                   \
        A0_ = *(const bf16x8*)(b_ + abase + 1 * 4096 + 0 * 256);     \
        A1_ = *(const bf16x8*)(b_ + abase + 1 * 4096 + 1 * 256);     \
        A2_ = *(const bf16x8*)(b_ + abase + 1 * 4096 + 2 * 256);     \
        A3_ = *(const bf16x8*)(b_ + abase + 1 * 4096 + 3 * 256);     \
        acc[0][0] = MFMA32(A0_, XV##2, acc[0][0]);                   \
        acc[0][1] = MFMA32(A0_, XV##3, acc[0][1]);                   \
        acc[1][0] = MFMA32(A1_, XV##2, acc[1][0]);                   \
        acc[1][1] = MFMA32(A1_, XV##3, acc[1][1]);                   \
        acc[2][0] = MFMA32(A2_, XV##2, acc[2][0]);                   \
        acc[2][1] = MFMA32(A2_, XV##3, acc[2][1]);                   \
        acc[3][0] = MFMA32(A3_, XV##2, acc[3][0]);                   \
        acc[3][1] = MFMA32(A3_, XV##3, acc[3][1]);                   \
    } while (0)

    bf16x8 xA0, xA1, xA2, xA3, xB0, xB1, xB2, xB3;

    // ---------------- layer 1 ----------------
    // Prologue: W chunks 0..2 (6 gl_lds), x chunks 0,1 (8 loads). 14 in flight.
    stageW(sl0, 0); stageW(sl1, 1); stageW(sl2, 2);
    LOADX(xA, 0); LOADX(xB, 1);

    // Peeled kc=0..3 (ring/parity static). Iteration block B_kc = {stageW, LOADX}
    // is pinned between asm barriers; ledger: x(kc) in B_{kc-2}, 6 ops after ->
    // WAITBAR(6) steady; kc=0 needs only x1's 4 loads outstanding -> WAITBAR(4).
    WAITBAR(4); stageW(sl3, 3); COMP1(sl0, xA); LOADX(xA, 2);
    WAITBAR(6); stageW(sl0, 4); COMP1(sl1, xB); LOADX(xB, 3);
    WAITBAR(6); stageW(sl1, 5); COMP1(sl2, xA); LOADX(xA, 4);
    WAITBAR(6); stageW(sl2, 6); COMP1(sl3, xB); LOADX(xB, 5);

    for (int q = 1; q <= 4; ++q) {            // kc = 4q .. 4q+3  (4..19)
        const int kc = q * 4;
        WAITBAR(6); stageW(sl3, kc + 3); COMP1(sl0, xA); LOADX(xA, kc + 2);
        WAITBAR(6); stageW(sl0, kc + 4); COMP1(sl1, xB); LOADX(xB, kc + 3);
        WAITBAR(6); stageW(sl1, kc + 5); COMP1(sl2, xA); LOADX(xA, kc + 4);
        WAITBAR(6); stageW(sl2, kc + 6); COMP1(sl3, xB); LOADX(xB, kc + 5);
    }
    // Tail kc=20..23; W2 chunks 0,1 issued at kc=22 (land under epilogue-1).
    WAITBAR(6); stageW(sl3, 23); COMP1(sl0, xA); LOADX(xA, 22);
    WAITBAR(6);                  COMP1(sl1, xB); LOADX(xB, 23);
    WAITBAR(4); stage2(wt2, 0); stage2(wt2 + 8192, 1); COMP1(sl2, xA);
    WAITBAR(4);                  COMP1(sl3, xB);
    WAIT_LGK_BAR();   // ring reads drained before epilogue overwrites hbuf

    // epilogue 1: bias + relu -> hbuf [blk=h/8][m=256][8h]
#pragma unroll
    for (int i = 0; i < 4; ++i) {
#pragma unroll
        for (int g = 0; g < 4; ++g) {
            const int h0 = wm * 128 + i * 32 + g * 8 + 4 * hi;
            float4 bias = *(const float4*)(b1 + t * H_ + h0);
            const int blk = h0 >> 3;
#pragma unroll
            for (int j = 0; j < 2; ++j) {
                const int mm = wn * 64 + j * 32 + ln31;
                bf16x4 o;
                o[0] = (bf16_t)fmaxf(acc[i][j][4 * g + 0] + bias.x, 0.0f);
                o[1] = (bf16_t)fmaxf(acc[i][j][4 * g + 1] + bias.y, 0.0f);
                o[2] = (bf16_t)fmaxf(acc[i][j][4 * g + 2] + bias.z, 0.0f);
                o[3] = (bf16_t)fmaxf(acc[i][j][4 * g + 3] + bias.w, 0.0f);
                *(bf16x4*)(hbuf + (size_t)(blk * BM_ + mm) * 8 + 4 * hi) = o;
            }
        }
    }

#pragma unroll
    for (int i = 0; i < 4; ++i)
#pragma unroll
        for (int j = 0; j < 2; ++j)
#pragma unroll
            for (int e = 0; e < 16; ++e) acc[i][j][e] = 0.0f;

    // ---------------- layer 2: h2^T = W2^T · h1^T (wt2 ring-2) ----------------
    auto comp2 = [&](const bf16_t* wbuf, int kc) {
#pragma unroll
        for (int s = 0; s < 2; ++s) {
            const int kq = s * 2 + hi;
            bf16x8 A[4], Bf[2];
#pragma unroll
            for (int i = 0; i < 4; ++i)
                A[i] = *(const bf16x8*)(wbuf + (size_t)(kq * H_ + wm * 128 + i * 32 + ln31) * 8);
            const int blk = kc * 4 + kq;
#pragma unroll
            for (int j = 0; j < 2; ++j) {
                const int mm = wn * 64 + j * 32 + ln31;
                Bf[j] = *(const bf16x8*)(hbuf + (size_t)(blk * BM_ + mm) * 8);
            }
#pragma unroll
            for (int i = 0; i < 4; ++i)
#pragma unroll
                for (int j = 0; j < 2; ++j) acc[i][j] = MFMA32(A[i], Bf[j], acc[i][j]);
        }
    };

    for (int kc = 0; kc < KC2; ++kc) {
        if (kc < KC2 - 1) { WAITBAR(2); } else { WAITBAR(0); }
        comp2(wt2 + (kc & 1) * 8192, kc);
        WAIT_LGK_BAR();                               // readers drained pre-restage
        if (kc < KC2 - 2) stage2(wt2 + (kc & 1) * 8192, kc + 2);
    }

    // epilogue 2: bias + relu -> h2 (hbuf, same layout); stage W3 into w3s
    if (tid < H_) w3s[tid] = W3[t * H_ + tid];
#pragma unroll
    for (int i = 0; i < 4; ++i) {
#pragma unroll
        for (int g = 0; g < 4; ++g) {
            const int h0 = wm * 128 + i * 32 + g * 8 + 4 * hi;
            float4 bias = *(const float4*)(b2 + t * H_ + h0);
            const int blk = h0 >> 3;
#pragma unroll
            for (int j = 0; j < 2; ++j) {
                const int mm = wn * 64 + j * 32 + ln31;
                bf16x4 o;
                o[0] = (bf16_t)fmaxf(acc[i][j][4 * g + 0] + bias.x, 0.0f);
                o[1] = (bf16_t)fmaxf(acc[i][j][4 * g + 1] + bias.y, 0.0f);
                o[2] = (bf16_t)fmaxf(acc[i][j][4 * g + 2] + bias.z, 0.0f);
                o[3] = (bf16_t)fmaxf(acc[i][j][4 * g + 3] + bias.w, 0.0f);
                *(bf16x4*)(hbuf + (size_t)(blk * BM_ + mm) * 8 + 4 * hi) = o;
            }
        }
    }
    WAIT_LGK_BAR();   // own ds_writes drained, then barrier: h2 + w3s visible

    // ---------------- layer 3: out[m,t] = h2[m,:]·W3[t,:] + b3[t] ----------------
    {
        const int m = tid >> 1, seg = tid & 1;   // 2 threads/row, 128 h each
        float sum = 0.0f;
#pragma unroll
        for (int b = 0; b < 16; ++b) {
            const int blk = seg * 16 + b;
            const bf16x8 v = *(const bf16x8*)(hbuf + (size_t)(blk * BM_ + m) * 8);
            const float* w = w3s + blk * 8;
#pragma unroll
            for (int e = 0; e < 8; ++e) sum += (float)v[e] * w[e];
        }
        sum += __shfl_xor(sum, 1);
        if (seg == 0) out[(size_t)(m0 + m) * T_ + t] = sum + b3[t];
    }
#undef LOADX
#undef COMP1
}

extern "C" void kernel_launch(void* const* d_in, const int* in_sizes, int n_in,
                              void* d_out, int out_size, void* d_ws, size_t ws_size,
                              hipStream_t stream) {
    const float* x  = (const float*)d_in[0];
    const float* W1 = (const float*)d_in[1];
    const float* b1 = (const float*)d_in[2];
    const float* W2 = (const float*)d_in[3];
    const float* b2 = (const float*)d_in[4];
    const float* W3 = (const float*)d_in[5];
    const float* b3 = (const float*)d_in[6];
    float* out = (float*)d_out;

    const size_t nx  = (size_t)B_ * IN_;        // 3,145,728
    const size_t nw1 = (size_t)T_ * IN_ * H_;   // 25,165,824

    bf16_t* xt  = (bf16_t*)d_ws;
    bf16_t* w1t = xt + nx;
    bf16_t* w2t = w1t + nw1;

    prep_all<<<dim3(5632), 256, 0, stream>>>(x, xt, W1, w1t, W2, w2t);
    mtmlp_fused5<<<dim3(2048), 512, 0, stream>>>(xt, w1t, b1, w2t, b2, W3, b3, out);
}